// Round 1
// baseline (502.437 us; speedup 1.0000x reference)
//
#include <hip/hip_runtime.h>

// RNN: B=1024, T=512, E=64, H=128, OUT=2, VOCAB=4411
// Fully fused: embedding gather + input projection + 512-step tanh recurrence
// + linear head in ONE kernel. One batch row per 128-thread block; thread j
// owns hidden unit j and keeps W_hh[j][:] (128 f32) + W_ih[j][:] (64 f32) in
// registers. h lives in LDS (double-buffered, broadcast reads), 1 barrier/step.

constexpr int Bc = 1024;
constexpr int Tc = 512;
constexpr int Ec = 64;
constexpr int Hc = 128;
constexpr int OUTc = 2;

__global__ __launch_bounds__(Hc, 2) void rnn_fused(
    const int* __restrict__ inputs,      // [B, T]
    const float* __restrict__ emb_table, // [VOCAB, E]
    const float* __restrict__ W_ih,      // [H, E]
    const float* __restrict__ W_hh,      // [H, H]
    const float* __restrict__ b_ih,      // [H]
    const float* __restrict__ b_hh,      // [H]
    const float* __restrict__ W_lin,     // [OUT, H]
    const float* __restrict__ b_lin,     // [OUT]
    float* __restrict__ out)             // [B, OUT]
{
    const int j   = threadIdx.x;   // hidden index 0..127
    const int row = blockIdx.x;    // batch row

    __shared__ float h_buf[2][Hc];
    __shared__ int   toks[Tc];
    __shared__ float red[2 * Hc];

    // Cooperative token load for this row (coalesced, 2 KB).
    for (int i = j; i < Tc; i += Hc) toks[i] = inputs[row * Tc + i];

    // Per-thread weight rows in registers (full unroll -> VGPRs).
    float w_hh[Hc];
    float w_ih[Ec];
#pragma unroll
    for (int k = 0; k < Hc; k += 4)
        *(float4*)&w_hh[k] = *(const float4*)(W_hh + j * Hc + k);
#pragma unroll
    for (int k = 0; k < Ec; k += 4)
        *(float4*)&w_ih[k] = *(const float4*)(W_ih + j * Ec + k);

    const float bias = b_ih[j] + b_hh[j];

    h_buf[0][j] = 0.0f;
    __syncthreads();

    int cur = 0;
    float hn = 0.0f;
    for (int t = 0; t < Tc; ++t) {
        const int tok = toks[t];
        const float* erow = emb_table + (long)tok * Ec;

        float a0 = bias, a1 = 0.0f, a2 = 0.0f, a3 = 0.0f;

        // x_t[j] = dot(emb_table[tok], W_ih[j]) — broadcast global (L1/L2-hot)
#pragma unroll
        for (int k = 0; k < Ec; k += 4) {
            const float4 e = *(const float4*)(erow + k);
            a0 = fmaf(e.x, w_ih[k + 0], a0);
            a1 = fmaf(e.y, w_ih[k + 1], a1);
            a2 = fmaf(e.z, w_ih[k + 2], a2);
            a3 = fmaf(e.w, w_ih[k + 3], a3);
        }

        // + dot(h, W_hh[j]) — broadcast LDS reads (same-address: conflict-free)
        const float* hb = h_buf[cur];
#pragma unroll
        for (int k = 0; k < Hc; k += 4) {
            const float4 hv = *(const float4*)(hb + k);
            a0 = fmaf(hv.x, w_hh[k + 0], a0);
            a1 = fmaf(hv.y, w_hh[k + 1], a1);
            a2 = fmaf(hv.z, w_hh[k + 2], a2);
            a3 = fmaf(hv.w, w_hh[k + 3], a3);
        }

        const float z  = (a0 + a1) + (a2 + a3);
        // tanh(z) = 1 - 2/(exp(2z)+1); exact at saturation (inf -> 1, 0 -> -1)
        const float ex = __expf(2.0f * z);
        hn = 1.0f - 2.0f / (ex + 1.0f);

        cur ^= 1;
        h_buf[cur][j] = hn;
        __syncthreads();
    }

    // Linear head: out[row][o] = sum_j h[j] * W_lin[o][j] + b_lin[o]
    red[j]      = hn * W_lin[j];
    red[Hc + j] = hn * W_lin[Hc + j];
    __syncthreads();
    if (j < OUTc) {
        float s = b_lin[j];
        for (int k = 0; k < Hc; ++k) s += red[j * Hc + k];
        out[row * OUTc + j] = s;
    }
}

extern "C" void kernel_launch(void* const* d_in, const int* in_sizes, int n_in,
                              void* d_out, int out_size, void* d_ws, size_t ws_size,
                              hipStream_t stream) {
    const int*   inputs    = (const int*)d_in[0];
    const float* emb_table = (const float*)d_in[1];
    const float* W_ih      = (const float*)d_in[2];
    const float* W_hh      = (const float*)d_in[3];
    const float* b_ih      = (const float*)d_in[4];
    const float* b_hh      = (const float*)d_in[5];
    const float* W_lin     = (const float*)d_in[6];
    const float* b_lin     = (const float*)d_in[7];
    float* out = (float*)d_out;

    rnn_fused<<<Bc, Hc, 0, stream>>>(inputs, emb_table, W_ih, W_hh,
                                     b_ih, b_hh, W_lin, b_lin, out);
}